// Round 4
// baseline (233.635 us; speedup 1.0000x reference)
//
#include <hip/hip_runtime.h>

#define NG   16
#define HID  256

typedef float f32x4 __attribute__((ext_vector_type(4)));

// Output layout (floats): visit (BT,256) | tokens (BT,16,256) | weights (BT,16)
constexpr size_t BT      = 32ull * 2048ull;            // 65536 rows
constexpr size_t TOK_OFF = BT * HID;
constexpr size_t WT_OFF  = TOK_OFF + BT * NG * HID;

__device__ __forceinline__ float fast_tanh(float v) {
    // tanh(x) = 1 - 2/(exp(2x)+1); ~1ulp exp/rcp, output threshold 3.7e-2
    float e = __expf(2.0f * v);
    return 1.0f - 2.0f * __builtin_amdgcn_rcpf(e + 1.0f);
}

__device__ __forceinline__ float rfl(float v) {      // wave-uniform -> SGPR
    return __int_as_float(__builtin_amdgcn_readfirstlane(__float_as_int(v)));
}
__device__ __forceinline__ float rln(float v, int l) { // const-lane -> SGPR
    return __int_as_float(__builtin_amdgcn_readlane(__float_as_int(v), l));
}

__global__ __launch_bounds__(256) void gve_kernel(
    const float*  __restrict__ x,      // (BT,64)
    const f32x4*  __restrict__ w_gp4,  // (64) float4
    const f32x4*  __restrict__ b_gp4,
    const f32x4*  __restrict__ w_sp4,
    const float*  __restrict__ b_sp,
    float* __restrict__ out)
{
    const int lane = threadIdx.x & 63;
    const int wv   = threadIdx.x >> 6;
    const size_t row = (size_t)blockIdx.x * 4 + wv;   // one (b,t) row per wave

    // ---- stage x row: per-wave slot, intra-wave only -> NO barrier ----
    __shared__ float sx[4][64];
    sx[wv][lane] = x[row * 64 + lane];
    // (compiler inserts lgkmcnt wait before the dependent reads below)

    // ---- per-lane hidden slice: h = 4*lane .. 4*lane+3 ----
    const f32x4 wg = w_gp4[lane];
    const f32x4 bg = b_gp4[lane];
    const f32x4 ws = w_sp4[lane];

    // ---- group means (wave-uniform -> SGPRs) ----
    // groups are contiguous segments, sizes [1,3,5,7] tiled x4
    float gv[NG];
    {
        const float rcnt[4] = {1.0f, 1.0f/3.0f, 0.2f, 1.0f/7.0f};
        #pragma unroll
        for (int g = 0; g < NG; ++g) {
            const int chunk = g >> 2, sub = g & 3;
            const int begs[5] = {0, 1, 4, 9, 16};
            const int beg = chunk * 16 + begs[sub];
            const int end = chunk * 16 + begs[sub + 1];
            float s = 0.0f;
            #pragma unroll
            for (int i = beg; i < end; ++i) s += sx[wv][i];   // uniform addr: broadcast
            gv[g] = rfl(s * rcnt[sub]);                        // -> SGPR
        }
    }

    // ---- fused: token store (NT) + score partials ----
    float* __restrict__ tokp = out + TOK_OFF + row * (NG * HID) + 4 * lane;
    float part[NG];
    #pragma unroll
    for (int g = 0; g < NG; ++g) {
        f32x4 t;
        t.x = fmaf(gv[g], wg.x, bg.x);
        t.y = fmaf(gv[g], wg.y, bg.y);
        t.z = fmaf(gv[g], wg.z, bg.z);
        t.w = fmaf(gv[g], wg.w, bg.w);
        __builtin_nontemporal_store(t, (f32x4*)(tokp + g * HID));  // 1 KB/wave-store
        part[g] = fast_tanh(t.x) * ws.x + fast_tanh(t.y) * ws.y
                + fast_tanh(t.z) * ws.z + fast_tanh(t.w) * ws.w;
    }

    // ---- split butterfly reduce over 64 lanes (32 shuffles) ----
    #pragma unroll
    for (int g = 0; g < NG; ++g) part[g] += __shfl_xor(part[g], 32, 64);
    const bool b5 = (lane & 32) != 0;
    float v8[8];
    #pragma unroll
    for (int j = 0; j < 8; ++j) v8[j] = b5 ? part[j + 8] : part[j];
    #pragma unroll
    for (int j = 0; j < 8; ++j) v8[j] += __shfl_xor(v8[j], 16, 64);
    const bool b4 = (lane & 16) != 0;
    float v4_[4];
    #pragma unroll
    for (int j = 0; j < 4; ++j) v4_[j] = b4 ? v8[j + 4] : v8[j];
    #pragma unroll
    for (int j = 0; j < 4; ++j) v4_[j] += __shfl_xor(v4_[j], 8, 64);
    const bool b3 = (lane & 8) != 0;
    float v2_[2];
    #pragma unroll
    for (int j = 0; j < 2; ++j) v2_[j] = b3 ? v4_[j + 2] : v4_[j];
    #pragma unroll
    for (int j = 0; j < 2; ++j) v2_[j] += __shfl_xor(v2_[j], 4, 64);
    const bool b2 = (lane & 4) != 0;
    float v1 = b2 ? v2_[1] : v2_[0];
    v1 += __shfl_xor(v1, 2, 64);
    v1 += __shfl_xor(v1, 1, 64);
    // every lane now holds score-sum for group g = lane>>2

    // ---- softmax, fully in-register ----
    const float score = v1 + b_sp[0];
    float m = score;
    m = fmaxf(m, __shfl_xor(m, 4, 64));
    m = fmaxf(m, __shfl_xor(m, 8, 64));
    m = fmaxf(m, __shfl_xor(m, 16, 64));
    m = fmaxf(m, __shfl_xor(m, 32, 64));          // max over all 16 groups
    float e = __expf(score - m);
    float s = e;
    s += __shfl_xor(s, 4, 64);
    s += __shfl_xor(s, 8, 64);
    s += __shfl_xor(s, 16, 64);
    s += __shfl_xor(s, 32, 64);                   // sum: one lane per group
    const float w = e / s;                        // weight for g = lane>>2

    // ---- visit: weights to SGPR (const-lane readlane), recompute tokens ----
    f32x4 visit = {0.0f, 0.0f, 0.0f, 0.0f};
    #pragma unroll
    for (int g = 0; g < NG; ++g) {
        const float wt = rln(w, 4 * g);           // SGPR broadcast
        visit.x = fmaf(wt, fmaf(gv[g], wg.x, bg.x), visit.x);
        visit.y = fmaf(wt, fmaf(gv[g], wg.y, bg.y), visit.y);
        visit.z = fmaf(wt, fmaf(gv[g], wg.z, bg.z), visit.z);
        visit.w = fmaf(wt, fmaf(gv[g], wg.w, bg.w), visit.w);
    }
    __builtin_nontemporal_store(visit, (f32x4*)(out + row * HID + 4 * lane));

    // ---- weights: 16 lanes scalar NT store (64 B per row) ----
    const float wl = __shfl(w, (lane & 15) * 4, 64);
    if (lane < NG)
        __builtin_nontemporal_store(wl, out + WT_OFF + row * NG + lane);
}

extern "C" void kernel_launch(void* const* d_in, const int* in_sizes, int n_in,
                              void* d_out, int out_size, void* d_ws, size_t ws_size,
                              hipStream_t stream) {
    (void)in_sizes; (void)n_in; (void)out_size; (void)d_ws; (void)ws_size;
    const float*  x    = (const float*)d_in[0];
    const f32x4*  w_gp = (const f32x4*)d_in[1];
    const f32x4*  b_gp = (const f32x4*)d_in[2];
    const f32x4*  w_sp = (const f32x4*)d_in[3];
    const float*  b_sp = (const float*)d_in[4];
    float* out = (float*)d_out;

    gve_kernel<<<dim3((unsigned)(BT / 4)), dim3(256), 0, stream>>>(
        x, w_gp, b_gp, w_sp, b_sp, out);
}

// Round 5
// 232.214 us; speedup vs baseline: 1.0061x; 1.0061x over previous
//
#include <hip/hip_runtime.h>

#define NG   16
#define HID  256

typedef float f32x4 __attribute__((ext_vector_type(4)));

// Output layout (floats): visit (BT,256) | tokens (BT,16,256) | weights (BT,16)
constexpr size_t BT      = 32ull * 2048ull;            // 65536 rows
constexpr size_t TOK_OFF = BT * HID;
constexpr size_t WT_OFF  = TOK_OFF + BT * NG * HID;

__device__ __forceinline__ float fast_tanh(float v) {
    // tanh(x) = 1 - 2/(exp(2x)+1); ~1ulp exp/rcp, output threshold 3.7e-2
    float e = __expf(2.0f * v);
    return 1.0f - 2.0f * __builtin_amdgcn_rcpf(e + 1.0f);
}
__device__ __forceinline__ float rfl(float v) {      // wave-uniform -> SGPR
    return __int_as_float(__builtin_amdgcn_readfirstlane(__float_as_int(v)));
}
__device__ __forceinline__ float rln(float v, int l) { // const-lane -> SGPR
    return __int_as_float(__builtin_amdgcn_readlane(__float_as_int(v), l));
}

__global__ __launch_bounds__(256) void gve_kernel(
    const float*  __restrict__ x,      // (BT,64)
    const f32x4*  __restrict__ w_gp4,  // (64) float4
    const f32x4*  __restrict__ b_gp4,
    const f32x4*  __restrict__ w_sp4,
    const float*  __restrict__ b_sp,
    float* __restrict__ out)
{
    const int lane = threadIdx.x & 63;
    const int wv   = threadIdx.x >> 6;
    const size_t row0 = ((size_t)blockIdx.x * 4 + wv) * 4;  // 4 rows per wave

    // ---- one coalesced 1 KB load = this wave's 4 x-rows; stage in LDS ----
    __shared__ float sx[4][256];   // per-wave slot, intra-wave only: no barrier
    __shared__ float swt[4][64];   // per-wave weight staging (4 rows x 16 g)
    const f32x4 xl = ((const f32x4*)x)[row0 * 16 + lane];
    ((f32x4*)sx[wv])[lane] = xl;

    // ---- per-lane hidden slice: h = 4*lane .. 4*lane+3 (loaded once) ----
    const f32x4 wg = w_gp4[lane];
    const f32x4 bg = b_gp4[lane];
    const f32x4 ws = w_sp4[lane];
    const float bsp = b_sp[0];

    #pragma unroll 1   // keep VGPRs low: rows processed serially per wave
    for (int j = 0; j < 4; ++j) {
        const size_t row = row0 + j;
        const float* sxr = sx[wv] + j * 64;

        // ---- group means (wave-uniform -> SGPRs); segments [1,3,5,7] x4 ----
        float gv[NG];
        {
            const float rcnt[4] = {1.0f, 1.0f/3.0f, 0.2f, 1.0f/7.0f};
            #pragma unroll
            for (int g = 0; g < NG; ++g) {
                const int chunk = g >> 2, sub = g & 3;
                const int begs[5] = {0, 1, 4, 9, 16};
                const int beg = chunk * 16 + begs[sub];
                const int end = chunk * 16 + begs[sub + 1];
                float s = 0.0f;
                #pragma unroll
                for (int i = beg; i < end; ++i) s += sxr[i];  // uniform: broadcast
                gv[g] = rfl(s * rcnt[sub]);                   // -> SGPR
            }
        }

        // ---- fused: token store (NT, 1 KB/wave-store) + score partials ----
        float* __restrict__ tokp = out + TOK_OFF + row * (NG * HID) + 4 * lane;
        float part[NG];
        #pragma unroll
        for (int g = 0; g < NG; ++g) {
            f32x4 t;
            t.x = fmaf(gv[g], wg.x, bg.x);
            t.y = fmaf(gv[g], wg.y, bg.y);
            t.z = fmaf(gv[g], wg.z, bg.z);
            t.w = fmaf(gv[g], wg.w, bg.w);
            __builtin_nontemporal_store(t, (f32x4*)(tokp + g * HID));
            part[g] = fast_tanh(t.x) * ws.x + fast_tanh(t.y) * ws.y
                    + fast_tanh(t.z) * ws.z + fast_tanh(t.w) * ws.w;
        }

        // ---- split butterfly reduce over 64 lanes (32 shuffles) ----
        #pragma unroll
        for (int g = 0; g < NG; ++g) part[g] += __shfl_xor(part[g], 32, 64);
        const bool b5 = (lane & 32) != 0;
        float v8[8];
        #pragma unroll
        for (int q = 0; q < 8; ++q) v8[q] = b5 ? part[q + 8] : part[q];
        #pragma unroll
        for (int q = 0; q < 8; ++q) v8[q] += __shfl_xor(v8[q], 16, 64);
        const bool b4 = (lane & 16) != 0;
        float v4_[4];
        #pragma unroll
        for (int q = 0; q < 4; ++q) v4_[q] = b4 ? v8[q + 4] : v8[q];
        #pragma unroll
        for (int q = 0; q < 4; ++q) v4_[q] += __shfl_xor(v4_[q], 8, 64);
        const bool b3 = (lane & 8) != 0;
        float v2_[2];
        #pragma unroll
        for (int q = 0; q < 2; ++q) v2_[q] = b3 ? v4_[q + 2] : v4_[q];
        #pragma unroll
        for (int q = 0; q < 2; ++q) v2_[q] += __shfl_xor(v2_[q], 4, 64);
        const bool b2 = (lane & 4) != 0;
        float v1 = b2 ? v2_[1] : v2_[0];
        v1 += __shfl_xor(v1, 2, 64);
        v1 += __shfl_xor(v1, 1, 64);
        // every lane holds score-sum for group g = lane>>2

        // ---- softmax, fully in-register ----
        const float score = v1 + bsp;
        float m = score;
        m = fmaxf(m, __shfl_xor(m, 4, 64));
        m = fmaxf(m, __shfl_xor(m, 8, 64));
        m = fmaxf(m, __shfl_xor(m, 16, 64));
        m = fmaxf(m, __shfl_xor(m, 32, 64));
        float e = __expf(score - m);
        float s = e;
        s += __shfl_xor(s, 4, 64);
        s += __shfl_xor(s, 8, 64);
        s += __shfl_xor(s, 16, 64);
        s += __shfl_xor(s, 32, 64);
        const float w = e / s;                    // weight for g = lane>>2

        // stash this row's 16 weights for the fused 256 B store at the end
        if ((lane & 3) == 0) swt[wv][j * 16 + (lane >> 2)] = w;

        // ---- visit: weights via const-lane readlane, recompute tokens ----
        f32x4 visit = {0.0f, 0.0f, 0.0f, 0.0f};
        #pragma unroll
        for (int g = 0; g < NG; ++g) {
            const float wt = rln(w, 4 * g);       // SGPR broadcast
            visit.x = fmaf(wt, fmaf(gv[g], wg.x, bg.x), visit.x);
            visit.y = fmaf(wt, fmaf(gv[g], wg.y, bg.y), visit.y);
            visit.z = fmaf(wt, fmaf(gv[g], wg.z, bg.z), visit.z);
            visit.w = fmaf(wt, fmaf(gv[g], wg.w, bg.w), visit.w);
        }
        __builtin_nontemporal_store(visit, (f32x4*)(out + row * HID + 4 * lane));
    }

    // ---- weights: one fully-active 256 B NT store covers the 4 rows ----
    const float wl = swt[wv][lane];               // lane = j*16 + g
    __builtin_nontemporal_store(wl, out + WT_OFF + row0 * NG + lane);
}

extern "C" void kernel_launch(void* const* d_in, const int* in_sizes, int n_in,
                              void* d_out, int out_size, void* d_ws, size_t ws_size,
                              hipStream_t stream) {
    (void)in_sizes; (void)n_in; (void)out_size; (void)d_ws; (void)ws_size;
    const float*  x    = (const float*)d_in[0];
    const f32x4*  w_gp = (const f32x4*)d_in[1];
    const f32x4*  b_gp = (const f32x4*)d_in[2];
    const f32x4*  w_sp = (const f32x4*)d_in[3];
    const float*  b_sp = (const float*)d_in[4];
    float* out = (float*)d_out;

    // 4 waves/block x 4 rows/wave = 16 rows/block
    gve_kernel<<<dim3((unsigned)(BT / 16)), dim3(256), 0, stream>>>(
        x, w_gp, b_gp, w_sp, b_sp, out);
}